// Round 10
// baseline (938.198 us; speedup 1.0000x reference)
//
#include <hip/hip_runtime.h>
#include <hip/hip_bf16.h>

#define DM 1024
#define NH 16
#define BB 8
#define SS 1024
#define MROWS (BB * SS)  // 8192

typedef _Float16 f16;
using f32x4 = __attribute__((ext_vector_type(4))) float;
using f16x8 = __attribute__((ext_vector_type(8))) _Float16;
using f16x4 = __attribute__((ext_vector_type(4))) _Float16;
using hf16x2 = __attribute__((ext_vector_type(2))) __fp16;  // cvt_pkrtz native type

using lds_ptr_t = __attribute__((address_space(3))) void*;
using glb_ptr_t = const __attribute__((address_space(1))) void*;

__device__ __forceinline__ void glds16(const void* g, void* l) {
  __builtin_amdgcn_global_load_lds((glb_ptr_t)g, (lds_ptr_t)l, 16, 0, 0);
}

// ---------------- cast kernels: fp32 -> fp16 -------------------------------
__global__ __launch_bounds__(256) void cast_kernel(const float* __restrict__ src,
                                                   f16* __restrict__ dst,
                                                   int n) {
  int i = (blockIdx.x * 256 + threadIdx.x) * 4;
  if (i < n) {
    float4 v = *reinterpret_cast<const float4*>(src + i);
    f16x4 o;
    o[0] = (f16)v.x; o[1] = (f16)v.y; o[2] = (f16)v.z; o[3] = (f16)v.w;
    *reinterpret_cast<f16x4*>(dst + i) = o;
  }
}

struct WC {
  const float *s0, *s1, *s2, *s3;
  f16 *d0, *d1, *d2, *d3;
};
// 4 weight matrices (1M elems each) in one launch; grid 4096
__global__ __launch_bounds__(256) void wcast_kernel(WC a) {
  const int seg = blockIdx.x >> 10;
  const int blk = blockIdx.x & 1023;
  const float* s = (seg == 0) ? a.s0 : (seg == 1) ? a.s1 : (seg == 2) ? a.s2 : a.s3;
  f16* d = (seg == 0) ? a.d0 : (seg == 1) ? a.d1 : (seg == 2) ? a.d2 : a.d3;
  const int i = (blk * 256 + threadIdx.x) * 4;
  float4 v = *reinterpret_cast<const float4*>(s + i);
  f16x4 o;
  o[0] = (f16)v.x; o[1] = (f16)v.y; o[2] = (f16)v.z; o[3] = (f16)v.w;
  *reinterpret_cast<f16x4*>(d + i) = o;
}

// ---------------- fused QKV projection GEMM --------------------------------
// C_z = A @ B_z^T + bias_z for z in {Q,K,V}; grid (64, 8, 3), block 256.
// z<2 -> f16 out [b,h,s,d]; z==2 -> f16 out [b,h,d,s] (V transposed).
struct QKVArgs {
  const f16 *A, *B0, *B1, *B2;
  const float *bi0, *bi1, *bi2;
  f16 *O0, *O1, *O2;
};
__global__ __launch_bounds__(256) void qkv_gemm(QKVArgs p) {
  __shared__ f16 As[128 * 32];
  __shared__ f16 Bs[128 * 32];
  const int t = threadIdx.x;
  const int lane = t & 63;
  const int w = t >> 6;
  const int wm = w >> 1, wn = w & 1;
  const int bm = blockIdx.x * 128;
  const int bn = blockIdx.y * 128;
  const int z = blockIdx.z;
  const int l15 = lane & 15;
  const int g = lane >> 4;

  const f16* Bmat = (z == 0) ? p.B0 : (z == 1) ? p.B1 : p.B2;
  const float* bias = (z == 0) ? p.bi0 : (z == 1) ? p.bi1 : p.bi2;

  const f16* a0 = p.A + (size_t)bm * DM;
  const f16* b0 = Bmat + (size_t)bn * DM;

  f32x4 acc[4][4] = {};

  const int c0 = w * 64 + lane;
  const int c1 = 256 + w * 64 + lane;

  for (int kt = 0; kt < DM / 32; ++kt) {
    const int k0 = kt * 32;
    glds16(a0 + (size_t)(c0 >> 2) * DM + k0 + (c0 & 3) * 8, As + (size_t)(w * 64) * 8);
    glds16(a0 + (size_t)(c1 >> 2) * DM + k0 + (c1 & 3) * 8, As + (size_t)(256 + w * 64) * 8);
    glds16(b0 + (size_t)(c0 >> 2) * DM + k0 + (c0 & 3) * 8, Bs + (size_t)(w * 64) * 8);
    glds16(b0 + (size_t)(c1 >> 2) * DM + k0 + (c1 & 3) * 8, Bs + (size_t)(256 + w * 64) * 8);
    __syncthreads();

    f16x8 af[4], bfr[4];
#pragma unroll
    for (int m = 0; m < 4; ++m)
      af[m] = *(const f16x8*)(As + (wm * 64 + m * 16 + l15) * 32 + g * 8);
#pragma unroll
    for (int n = 0; n < 4; ++n)
      bfr[n] = *(const f16x8*)(Bs + (wn * 64 + n * 16 + l15) * 32 + g * 8);
#pragma unroll
    for (int m = 0; m < 4; ++m)
#pragma unroll
      for (int n = 0; n < 4; ++n)
        acc[m][n] = __builtin_amdgcn_mfma_f32_16x16x32_f16(af[m], bfr[n], acc[m][n], 0, 0, 0);
    __syncthreads();
  }

  f16* Out = (z == 0) ? p.O0 : (z == 1) ? p.O1 : p.O2;
#pragma unroll
  for (int n = 0; n < 4; ++n) {
    const int j = bn + wn * 64 + n * 16 + l15;
    const float bj = bias[j];
#pragma unroll
    for (int m = 0; m < 4; ++m) {
      const int ib = bm + wm * 64 + m * 16 + g * 4;
#pragma unroll
      for (int r = 0; r < 4; ++r) {
        const int i = ib + r;
        const float val = acc[m][n][r] + bj;
        const int b = i >> 10, s = i & 1023, h = j >> 6, d = j & 63;
        if (z < 2) {
          Out[((size_t)((b * 16 + h) * 1024 + s)) * 64 + d] = (f16)val;  // [b,h,s,d]
        } else {
          Out[((size_t)((b * 16 + h) * 64 + d)) * 1024 + s] = (f16)val;  // [b,h,d,s]
        }
      }
    }
  }
}

// ---------------- output GEMM: d_out = Hd @ Wo^T + bo (fp32 out) -----------
__global__ __launch_bounds__(256) void gemm_out(const f16* __restrict__ A,
                                                const f16* __restrict__ Bm,
                                                const float* __restrict__ bias,
                                                float* __restrict__ Out) {
  __shared__ f16 As[128 * 32];
  __shared__ f16 Bs[128 * 32];
  const int t = threadIdx.x;
  const int lane = t & 63;
  const int w = t >> 6;
  const int wm = w >> 1, wn = w & 1;
  const int bm = blockIdx.x * 128;
  const int bn = blockIdx.y * 128;
  const int l15 = lane & 15;
  const int g = lane >> 4;

  const f16* a0 = A + (size_t)bm * DM;
  const f16* b0 = Bm + (size_t)bn * DM;

  f32x4 acc[4][4] = {};

  const int c0 = w * 64 + lane;
  const int c1 = 256 + w * 64 + lane;

  for (int kt = 0; kt < DM / 32; ++kt) {
    const int k0 = kt * 32;
    glds16(a0 + (size_t)(c0 >> 2) * DM + k0 + (c0 & 3) * 8, As + (size_t)(w * 64) * 8);
    glds16(a0 + (size_t)(c1 >> 2) * DM + k0 + (c1 & 3) * 8, As + (size_t)(256 + w * 64) * 8);
    glds16(b0 + (size_t)(c0 >> 2) * DM + k0 + (c0 & 3) * 8, Bs + (size_t)(w * 64) * 8);
    glds16(b0 + (size_t)(c1 >> 2) * DM + k0 + (c1 & 3) * 8, Bs + (size_t)(256 + w * 64) * 8);
    __syncthreads();

    f16x8 af[4], bfr[4];
#pragma unroll
    for (int m = 0; m < 4; ++m)
      af[m] = *(const f16x8*)(As + (wm * 64 + m * 16 + l15) * 32 + g * 8);
#pragma unroll
    for (int n = 0; n < 4; ++n)
      bfr[n] = *(const f16x8*)(Bs + (wn * 64 + n * 16 + l15) * 32 + g * 8);
#pragma unroll
    for (int m = 0; m < 4; ++m)
#pragma unroll
      for (int n = 0; n < 4; ++n)
        acc[m][n] = __builtin_amdgcn_mfma_f32_16x16x32_f16(af[m], bfr[n], acc[m][n], 0, 0, 0);
    __syncthreads();
  }

#pragma unroll
  for (int n = 0; n < 4; ++n) {
    const int j = bn + wn * 64 + n * 16 + l15;
    const float bj = bias[j];
#pragma unroll
    for (int m = 0; m < 4; ++m) {
      const int ib = bm + wm * 64 + m * 16 + g * 4;
#pragma unroll
      for (int r = 0; r < 4; ++r) {
        const int i = ib + r;
        Out[(size_t)i * DM + j] = acc[m][n][r] + bj;
      }
    }
  }
}

// ---------------- fused attention v4.1 -------------------------------------
// Swapped QK^T (lane owns k=g*4+r, q=l15) + LDS-atomic batch-denominator +
// intra-wave P redistribution. 2 k-tiles per barrier group -> 1 barrier/tile.
// grid 512 (1-D, XCD-swizzled), block 512 (wave = batch).
#define DSTR 67  // Dsum row stride (dwords): good atomic bank spread
#define PSTR 40  // Pscr row stride (f16): 80B rows -> 16B-aligned b128 reads

__global__ __launch_bounds__(512, 4) void attn_kernel(const f16* __restrict__ Qr,
                                                      const f16* __restrict__ Kr,
                                                      const f16* __restrict__ Vt,
                                                      f16* __restrict__ Hd) {
  __shared__ float Dsum[2][32 * DSTR];            // 17.2 KB, dbuf over groups
  __shared__ unsigned short Pscr[8][32 * PSTR];   // 20.5 KB, per-wave scratch

  const int t = threadIdx.x;
  const int lane = t & 63;
  const int b = t >> 6;  // batch = wave id
  const int l15 = lane & 15;
  const int g = lane >> 4;

  // XCD swizzle: XCD x gets logical blocks [x*64, x*64+64) -> 2 heads per XCD
  const int bid = blockIdx.x;
  const int L = (bid & 7) * 64 + (bid >> 3);
  const int h = L >> 5;
  const int qt = L & 31;

  const size_t plane = (size_t)(b * NH + h) * SS * 64;
  const f16* Qp = Qr + plane;                       // [s][d]
  const f16* Kp = Kr + plane;                       // [s][d]
  const f16* Vp = Vt + (size_t)(b * NH + h) * 64 * SS;  // [d][s]

  // Q B-fragments in registers for all tiles
  f16x8 qfr[2][2];
#pragma unroll
  for (int qf = 0; qf < 2; ++qf)
#pragma unroll
    for (int db = 0; db < 2; ++db)
      qfr[qf][db] = *(const f16x8*)(Qp + (size_t)(qt * 32 + qf * 16 + l15) * 64 + db * 32 + g * 8);

  // zero Dsum[0]
  for (int p = t; p < 32 * DSTR; p += 512) Dsum[0][p] = 0.f;
  __syncthreads();

  f32x4 oacc[2][4] = {};
  float e[2][2][2][4];  // [t2][kf][qf][r]

  for (int grp = 0; grp < 16; ++grp) {
    const int cur = grp & 1, nxt = cur ^ 1;
    // ---- P1: QK^T (swapped), exp, atomic denominator, both tiles ----------
#pragma unroll
    for (int t2 = 0; t2 < 2; ++t2) {
      const int kt = grp * 2 + t2;
      f32x4 sacc[2][2] = {};
      // per-db K loads: only 2 f16x8 K-regs live at a time (VGPR guard)
#pragma unroll
      for (int db = 0; db < 2; ++db) {
        f16x8 k0 = *(const f16x8*)(Kp + (size_t)(kt * 32 + 0 * 16 + l15) * 64 + db * 32 + g * 8);
        f16x8 k1 = *(const f16x8*)(Kp + (size_t)(kt * 32 + 1 * 16 + l15) * 64 + db * 32 + g * 8);
        __builtin_amdgcn_s_setprio(1);
#pragma unroll
        for (int qf = 0; qf < 2; ++qf) {
          sacc[0][qf] = __builtin_amdgcn_mfma_f32_16x16x32_f16(k0, qfr[qf][db], sacc[0][qf], 0, 0, 0);
          sacc[1][qf] = __builtin_amdgcn_mfma_f32_16x16x32_f16(k1, qfr[qf][db], sacc[1][qf], 0, 0, 0);
        }
        __builtin_amdgcn_s_setprio(0);
      }
#pragma unroll
      for (int kf = 0; kf < 2; ++kf)
#pragma unroll
        for (int qf = 0; qf < 2; ++qf)
#pragma unroll
          for (int r = 0; r < 4; ++r) {
            const float ev = __expf(sacc[kf][qf][r]);
            e[t2][kf][qf][r] = ev;
            atomicAdd(&Dsum[cur][(qf * 16 + l15) * DSTR + t2 * 32 + kf * 16 + g * 4 + r], ev);
          }
    }
    __syncthreads();
    // ---- P2: Dsum -> 1/Dsum in place; zero next buffer --------------------
    for (int p = t; p < 2048; p += 512) {
      const int idx = (p >> 6) * DSTR + (p & 63);
      Dsum[cur][idx] = __builtin_amdgcn_rcpf(Dsum[cur][idx]);
      Dsum[nxt][idx] = 0.f;
    }
    __syncthreads();
    // ---- P3: scale, pack, intra-wave redistribute, PV ---------------------
#pragma unroll
    for (int t2 = 0; t2 < 2; ++t2) {
      const int kt = grp * 2 + t2;
#pragma unroll
      for (int kf = 0; kf < 2; ++kf)
#pragma unroll
        for (int qf = 0; qf < 2; ++qf) {
          const int dbase = (qf * 16 + l15) * DSTR + t2 * 32 + kf * 16 + g * 4;
          const float p0 = e[t2][kf][qf][0] * Dsum[cur][dbase + 0];
          const float p1 = e[t2][kf][qf][1] * Dsum[cur][dbase + 1];
          const float p2 = e[t2][kf][qf][2] * Dsum[cur][dbase + 2];
          const float p3 = e[t2][kf][qf][3] * Dsum[cur][dbase + 3];
          union { hf16x2 h; unsigned u; } ulo, uhi;
          ulo.h = __builtin_amdgcn_cvt_pkrtz(p0, p1);
          uhi.h = __builtin_amdgcn_cvt_pkrtz(p2, p3);
          uint2 wv; wv.x = ulo.u; wv.y = uhi.u;
          *reinterpret_cast<uint2*>(&Pscr[b][(qf * 16 + l15) * PSTR + kf * 16 + g * 4]) = wv;
        }
      // compiler fence: Pscr stores must be emitted before the gather below.
      // HW side is safe: same-wave DS ops complete in program order.
      asm volatile("" ::: "memory");
      f16x8 pf[2];
#pragma unroll
      for (int qf = 0; qf < 2; ++qf)
        pf[qf] = *(const f16x8*)&Pscr[b][(qf * 16 + l15) * PSTR + g * 8];
      __builtin_amdgcn_s_setprio(1);
#pragma unroll
      for (int nf = 0; nf < 4; ++nf) {
        f16x8 vf = *(const f16x8*)(Vp + (size_t)(nf * 16 + l15) * SS + kt * 32 + g * 8);
#pragma unroll
        for (int qf = 0; qf < 2; ++qf)
          oacc[qf][nf] = __builtin_amdgcn_mfma_f32_16x16x32_f16(pf[qf], vf, oacc[qf][nf], 0, 0, 0);
      }
      __builtin_amdgcn_s_setprio(0);
    }
  }

  // ---- epilogue: heads [b, s, h*64+d] as f16
#pragma unroll
  for (int qf = 0; qf < 2; ++qf)
#pragma unroll
    for (int nf = 0; nf < 4; ++nf)
#pragma unroll
      for (int r = 0; r < 4; ++r) {
        const int srow = qt * 32 + qf * 16 + g * 4 + r;
        const int d = nf * 16 + l15;
        Hd[((size_t)(b * 1024 + srow)) * 1024 + h * 64 + d] = (f16)oacc[qf][nf][r];
      }
}

// ---------------- launch ---------------------------------------------------
extern "C" void kernel_launch(void* const* d_in, const int* in_sizes, int n_in,
                              void* d_out, int out_size, void* d_ws, size_t ws_size,
                              hipStream_t stream) {
  const float* x  = (const float*)d_in[0];
  const float* Wq = (const float*)d_in[1];
  const float* bq = (const float*)d_in[2];
  const float* Wk = (const float*)d_in[3];
  const float* bk = (const float*)d_in[4];
  const float* Wv = (const float*)d_in[5];
  const float* bv = (const float*)d_in[6];
  const float* Wo = (const float*)d_in[7];
  const float* bo = (const float*)d_in[8];

  char* ws = (char*)d_ws;
  const size_t MB = 1u << 20;
  f16* xf  = (f16*)(ws + 0 * MB);    // 16 MB (dead after QKV; reused as Hd)
  f16* Wqf = (f16*)(ws + 16 * MB);   // 2 MB
  f16* Wkf = (f16*)(ws + 18 * MB);   // 2 MB
  f16* Wvf = (f16*)(ws + 20 * MB);   // 2 MB
  f16* Wof = (f16*)(ws + 22 * MB);   // 2 MB
  f16* Qr  = (f16*)(ws + 24 * MB);   // 16 MB [b,h,s,d]
  f16* Kr  = (f16*)(ws + 40 * MB);   // 16 MB [b,h,s,d]
  f16* Vt  = (f16*)(ws + 56 * MB);   // 16 MB [b,h,d,s]
  f16* Hd  = xf;                     // alias: xf dead once projections done

  // casts (2 launches)
  cast_kernel<<<8192, 256, 0, stream>>>(x, xf, MROWS * DM);
  WC wc{Wq, Wk, Wv, Wo, Wqf, Wkf, Wvf, Wof};
  wcast_kernel<<<4096, 256, 0, stream>>>(wc);

  // fused Q/K/V projections: one dispatch, grid.z selects matrix
  QKVArgs qa{xf, Wqf, Wkf, Wvf, bq, bk, bv, Qr, Kr, Vt};
  qkv_gemm<<<dim3(MROWS / 128, DM / 128, 3), 256, 0, stream>>>(qa);

  // fused attention
  attn_kernel<<<512, 512, 0, stream>>>(Qr, Kr, Vt, Hd);

  // output projection -> fp32 d_out
  gemm_out<<<dim3(MROWS / 128, DM / 128), 256, 0, stream>>>(Hd, Wof, bo, (float*)d_out);
}